// Round 1
// baseline (392.693 us; speedup 1.0000x reference)
//
#include <hip/hip_runtime.h>
#include <hip/hip_bf16.h>

typedef _Float16 half4_t __attribute__((ext_vector_type(4)));
typedef _Float16 half8_t __attribute__((ext_vector_type(8)));
typedef float float4_t __attribute__((ext_vector_type(4)));

#define MFMA16(a, b, c) __builtin_amdgcn_mfma_f32_16x16x16f16((a), (b), (c), 0, 0, 0)

constexpr int Bb = 1024, Hh = 64, Ee = 512;
constexpr int EC = 32;               // e-chunk size
constexpr int NCHUNK = Ee / EC;      // 16
constexpr int QPAD = 520;            // sQ row stride in f16 (pad to kill bank conflicts, keep 16B align)
constexpr int WPAD = 520;
constexpr int MPAD = 40;
constexpr int TPAD = 40;
constexpr int SPAD = 65;
constexpr int PPAD = 68;
constexpr long CTX = (long)Bb * Hh * Ee;   // offset of attn in d_out

__global__ __launch_bounds__(512, 1)
void ovo_fused_kernel(const float* __restrict__ o1, const float* __restrict__ o2,
                      const float* __restrict__ o3, const float* __restrict__ qm,
                      const float* __restrict__ W, float* __restrict__ out)
{
    __shared__ _Float16 sQ[64 * QPAD];   // Q fp16 [g][f]
    __shared__ _Float16 sW[EC * WPAD];   // W chunk fp16 [e'][f]
    __shared__ _Float16 sM[64 * MPAD];   // mean chunk fp16 [h][e']
    __shared__ _Float16 sT[64 * TPAD];   // T chunk TRANSPOSED fp16 [g][e']
    __shared__ float    sS[64 * SPAD];   // score f32 [h][g]
    __shared__ _Float16 sP[64 * PPAD];   // attn fp16 [h][g]

    const int b    = blockIdx.x;
    const int t    = threadIdx.x;
    const int lane = t & 63;
    const int wid  = t >> 6;
    const int r16  = lane & 15;
    const int q4   = (lane >> 4) * 4;

    const long base = (long)b * Hh * Ee;

    // ---- stage Q = main[b] -> sQ (fp16) ----
    {
        const int row = t >> 3;              // 64 rows, 8 threads/row
        const int e0  = (t & 7) * 64;
        const float* src = qm + base + (long)row * Ee + e0;
        _Float16*    dst = sQ + row * QPAD + e0;
        #pragma unroll
        for (int j = 0; j < 8; ++j) {
            float4_t a = *(const float4_t*)(src + 8 * j);
            float4_t c = *(const float4_t*)(src + 8 * j + 4);
            half8_t h;
            h[0]=(_Float16)a[0]; h[1]=(_Float16)a[1]; h[2]=(_Float16)a[2]; h[3]=(_Float16)a[3];
            h[4]=(_Float16)c[0]; h[5]=(_Float16)c[1]; h[6]=(_Float16)c[2]; h[7]=(_Float16)c[3];
            *(half8_t*)(dst + 8 * j) = h;
        }
    }

    // ---- chunk-load machinery (global -> regs early, regs -> LDS after barrier) ----
    float4_t wreg[8];
    float4_t oreg[3];
    const int wrow = t >> 4;                 // 0..31 (W rows within chunk)
    const int wf0  = (t & 15) * 32;          // 16 threads cover 512 f
    const int mrow = t >> 3;                 // 0..63
    const int me0  = (t & 7) * 4;            // 8 threads * 4 f32 = 32 e

    auto issue_loads = [&](int c) {
        const float* wsrc = W + (long)(c * EC + wrow) * Ee + wf0;
        #pragma unroll
        for (int k = 0; k < 8; ++k) wreg[k] = *(const float4_t*)(wsrc + 4 * k);
        const long off = base + (long)mrow * Ee + c * EC + me0;
        oreg[0] = *(const float4_t*)(o1 + off);
        oreg[1] = *(const float4_t*)(o2 + off);
        oreg[2] = *(const float4_t*)(o3 + off);
    };
    auto commit_lds = [&]() {
        _Float16* dw = sW + wrow * WPAD + wf0;
        #pragma unroll
        for (int j = 0; j < 4; ++j) {
            float4_t a = wreg[2 * j], c = wreg[2 * j + 1];
            half8_t h;
            h[0]=(_Float16)a[0]; h[1]=(_Float16)a[1]; h[2]=(_Float16)a[2]; h[3]=(_Float16)a[3];
            h[4]=(_Float16)c[0]; h[5]=(_Float16)c[1]; h[6]=(_Float16)c[2]; h[7]=(_Float16)c[3];
            *(half8_t*)(dw + 8 * j) = h;
        }
        float4_t m = (oreg[0] + oreg[1] + oreg[2]) * (1.0f / 3.0f);
        half4_t hm;
        hm[0]=(_Float16)m[0]; hm[1]=(_Float16)m[1]; hm[2]=(_Float16)m[2]; hm[3]=(_Float16)m[3];
        *(half4_t*)(sM + mrow * MPAD + me0) = hm;
    };

    // ---- main loop: score[h,g] += M_chunk @ (W_chunk @ Q^T) ----
    float4_t scoreAcc[2] = {{0,0,0,0},{0,0,0,0}};
    const int te = wid >> 2;                 // 0..1  (T e'-tile)
    const int tg = wid & 3;                  // 0..3  (g-tile)

    issue_loads(0);
    for (int c = 0; c < NCHUNK; ++c) {
        __syncthreads();                     // prior chunk's stage-b done reading sM/sT
        commit_lds();
        __syncthreads();                     // sW, sM ready
        if (c + 1 < NCHUNK) issue_loads(c + 1);   // hide next chunk's HBM/L2 latency

        // stage-a: T tile (16 e' x 16 g), K = 512 over f
        float4_t accT = {0, 0, 0, 0};
        const _Float16* aw = sW + (te * 16 + r16) * WPAD + q4;
        const _Float16* bq = sQ + (tg * 16 + r16) * QPAD + q4;
        #pragma unroll
        for (int kk = 0; kk < 32; ++kk) {
            half4_t a  = *(const half4_t*)(aw + kk * 16);
            half4_t bb = *(const half4_t*)(bq + kk * 16);
            accT = MFMA16(a, bb, accT);
        }
        // write T transposed: sT[g][e']  (D rows are 4 consecutive e' -> b64 pack)
        {
            half4_t hv;
            hv[0]=(_Float16)accT[0]; hv[1]=(_Float16)accT[1];
            hv[2]=(_Float16)accT[2]; hv[3]=(_Float16)accT[3];
            *(half4_t*)(sT + (tg * 16 + r16) * TPAD + te * 16 + q4) = hv;
        }
        __syncthreads();                     // sT ready

        // stage-b: score tiles (ht, tg), K = 32 over e'
        #pragma unroll
        for (int hi = 0; hi < 2; ++hi) {
            const int ht = (wid >> 2) + 2 * hi;
            #pragma unroll
            for (int kk = 0; kk < 2; ++kk) {
                half4_t a  = *(const half4_t*)(sM + (ht * 16 + r16) * MPAD + kk * 16 + q4);
                half4_t bb = *(const half4_t*)(sT + (tg * 16 + r16) * TPAD + kk * 16 + q4);
                scoreAcc[hi] = MFMA16(a, bb, scoreAcc[hi]);
            }
        }
    }

    // ---- write score to LDS ----
    #pragma unroll
    for (int hi = 0; hi < 2; ++hi) {
        const int ht = (wid >> 2) + 2 * hi;
        #pragma unroll
        for (int j = 0; j < 4; ++j)
            sS[(ht * 16 + q4 + j) * SPAD + tg * 16 + r16] = scoreAcc[hi][j];
    }
    __syncthreads();

    // ---- softmax over g (waves 0-3: 16 rows each, 4 lanes/row) ----
    if (wid < 4) {
        const int r  = wid * 16 + r16;
        const int qd = lane >> 4;            // quarter of the row
        const float* srow = sS + r * SPAD + qd * 16;
        float v[16];
        float mx = -1e30f;
        #pragma unroll
        for (int i = 0; i < 16; ++i) { v[i] = srow[i]; mx = fmaxf(mx, v[i]); }
        mx = fmaxf(mx, __shfl_xor(mx, 16));
        mx = fmaxf(mx, __shfl_xor(mx, 32));
        float sum = 0.f;
        #pragma unroll
        for (int i = 0; i < 16; ++i) { v[i] = __expf(v[i] - mx); sum += v[i]; }
        sum += __shfl_xor(sum, 16);
        sum += __shfl_xor(sum, 32);
        const float inv = 1.0f / sum;
        float*    aout = out + CTX + ((long)b * 64 + r) * 64 + qd * 16;
        _Float16* prow = sP + r * PPAD + qd * 16;
        #pragma unroll
        for (int i = 0; i < 16; ++i) {
            float a = v[i] * inv;
            aout[i] = a;
            prow[i] = (_Float16)a;
        }
    }
    __syncthreads();

    // ---- context = P @ Q : wave w owns e-slice [64w, 64w+64) ----
    float4_t acc[4][4];
    #pragma unroll
    for (int i = 0; i < 4; ++i)
        #pragma unroll
        for (int j = 0; j < 4; ++j) acc[i][j] = (float4_t){0, 0, 0, 0};

    const int Eb = wid * 64;
    #pragma unroll
    for (int kk = 0; kk < 4; ++kk) {         // K = 64 over g
        half4_t aP[4], bQ[4];
        #pragma unroll
        for (int ht = 0; ht < 4; ++ht)
            aP[ht] = *(const half4_t*)(sP + (ht * 16 + r16) * PPAD + kk * 16 + q4);
        #pragma unroll
        for (int et = 0; et < 4; ++et) {
            half4_t h;
            #pragma unroll
            for (int j = 0; j < 4; ++j)
                h[j] = sQ[(kk * 16 + q4 + j) * QPAD + Eb + et * 16 + r16];
            bQ[et] = h;
        }
        #pragma unroll
        for (int ht = 0; ht < 4; ++ht)
            #pragma unroll
            for (int et = 0; et < 4; ++et)
                acc[ht][et] = MFMA16(aP[ht], bQ[et], acc[ht][et]);
    }

    // ---- store context (f32) ----
    #pragma unroll
    for (int ht = 0; ht < 4; ++ht)
        #pragma unroll
        for (int j = 0; j < 4; ++j) {
            const long row = (long)b * 64 + ht * 16 + q4 + j;
            float* orow = out + row * 512 + Eb;
            #pragma unroll
            for (int et = 0; et < 4; ++et)
                orow[et * 16 + r16] = acc[ht][et][j];
        }
}

extern "C" void kernel_launch(void* const* d_in, const int* in_sizes, int n_in,
                              void* d_out, int out_size, void* d_ws, size_t ws_size,
                              hipStream_t stream) {
    const float* o1 = (const float*)d_in[0];
    const float* o2 = (const float*)d_in[1];
    const float* o3 = (const float*)d_in[2];
    const float* qm = (const float*)d_in[3];
    const float* W  = (const float*)d_in[4];
    float* out = (float*)d_out;
    ovo_fused_kernel<<<dim3(Bb), dim3(512), 0, stream>>>(o1, o2, o3, qm, W, out);
}

// Round 2
// 323.421 us; speedup vs baseline: 1.2142x; 1.2142x over previous
//
#include <hip/hip_runtime.h>
#include <hip/hip_bf16.h>

typedef _Float16 half4_t __attribute__((ext_vector_type(4)));
typedef float    float4_t __attribute__((ext_vector_type(4)));

#define MFMA16(a, b, c) __builtin_amdgcn_mfma_f32_16x16x16f16((a), (b), (c), 0, 0, 0)

constexpr int Bb = 1024, Ee = 512;
constexpr int EC = 32;                 // e-chunk
constexpr int NCH = Ee / EC;           // 16
constexpr int MP = 36;                 // sM row stride (halves)
constexpr int SP = 65;                 // sS row stride (f32)
constexpr int PP = 68;                 // sP row stride (halves)
constexpr long CTX = (long)Bb * 64 * Ee;

// ---- pre-pass: pack W (f32 [e][f]) into A-fragment-layout fp16 ----
// W2[((ft*32 + ks)*64 + lane)*4 + j] = W[ks*16 + q4(lane) + j][ft*16 + r16(lane)]
__global__ void w_pack(const float* __restrict__ W, _Float16* __restrict__ W2) {
    const int t    = blockIdx.x * 256 + threadIdx.x;   // 65536 threads
    const int lane = t & 63, grp = t >> 6;
    const int ks   = grp & 31, ft = grp >> 5;
    const int r16  = lane & 15, q4 = (lane >> 4) * 4;
    half4_t h;
    #pragma unroll
    for (int j = 0; j < 4; ++j)
        h[j] = (_Float16)W[(long)(ks * 16 + q4 + j) * 512 + ft * 16 + r16];
    *(half4_t*)(W2 + (long)t * 4) = h;
}

__global__ __launch_bounds__(512, 4)
void ovo_main(const float* __restrict__ o1, const float* __restrict__ o2,
              const float* __restrict__ o3, const float* __restrict__ qm,
              const _Float16* __restrict__ W2, float* __restrict__ out)
{
    __shared__ _Float16 sM[2][64 * MP];   // mean chunk fp16 [h][e'], double-buffered
    __shared__ float    sS[64 * SP];      // score f32 [h][g]
    __shared__ _Float16 sP[64 * PP];      // attn fp16 [h][g]

    const int b    = blockIdx.x;
    const int t    = threadIdx.x;
    const int lane = t & 63;
    const int w    = t >> 6;              // wave 0..7, owns f/e-slice [64w, 64w+64)
    const int r16  = lane & 15;
    const int q4   = (lane >> 4) * 4;
    const long base = (long)b * 64 * 512;

    // zero score accumulator buffer (atomics target)
    for (int i = t; i < 64 * SP; i += 512) sS[i] = 0.f;

    // ---- mean-chunk staging: global -> regs -> LDS (fp16) ----
    const int mrow = t >> 3;              // 0..63 (h)
    const int me0  = (t & 7) * 4;         // 8 threads x 4 f32 = 32 e
    float4_t og0, og1, og2;
    auto issue = [&](int c) {
        const long off = base + (long)mrow * 512 + c * EC + me0;
        og0 = *(const float4_t*)(o1 + off);
        og1 = *(const float4_t*)(o2 + off);
        og2 = *(const float4_t*)(o3 + off);
    };
    auto commit = [&](int buf) {
        float4_t m = (og0 + og1 + og2) * (1.0f / 3.0f);
        half4_t h;
        h[0]=(_Float16)m[0]; h[1]=(_Float16)m[1]; h[2]=(_Float16)m[2]; h[3]=(_Float16)m[3];
        *(half4_t*)(&sM[buf][mrow * MP + me0]) = h;
    };

    // ---- phase 1: U^T tiles = W^T @ M^T, K=512 over e, accumulate in regs ----
    // accU[ftl][ht] holds U[ht*16+r16][w*64+ftl*16+q4+j]  (== phase-2 A-frag)
    float4_t accU[4][4];
    #pragma unroll
    for (int i = 0; i < 4; ++i)
        #pragma unroll
        for (int j = 0; j < 4; ++j) accU[i][j] = (float4_t){0,0,0,0};

    issue(0);
    commit(0);
    __syncthreads();

    for (int c = 0; c < NCH; ++c) {
        if (c + 1 < NCH) issue(c + 1);
        const int bufc = c & 1;
        #pragma unroll
        for (int kk = 0; kk < 2; ++kk) {
            const int ks = c * 2 + kk;
            half4_t A[4], Bm[4];
            #pragma unroll
            for (int ftl = 0; ftl < 4; ++ftl)
                A[ftl] = *(const half4_t*)(W2 + (((long)(w * 4 + ftl) * 32 + ks) * 64 + lane) * 4);
            #pragma unroll
            for (int ht = 0; ht < 4; ++ht)
                Bm[ht] = *(const half4_t*)(&sM[bufc][(ht * 16 + r16) * MP + kk * 16 + q4]);
            #pragma unroll
            for (int ftl = 0; ftl < 4; ++ftl)
                #pragma unroll
                for (int ht = 0; ht < 4; ++ht)
                    accU[ftl][ht] = MFMA16(A[ftl], Bm[ht], accU[ftl][ht]);
        }
        if (c + 1 < NCH) commit((c + 1) & 1);
        __syncthreads();
    }

    // ---- phase 2: score partial = U_slice @ Q^T (K = 64 over wave's f-slice) ----
    half4_t uh[4][4];
    #pragma unroll
    for (int ftl = 0; ftl < 4; ++ftl)
        #pragma unroll
        for (int ht = 0; ht < 4; ++ht) {
            half4_t h;
            h[0]=(_Float16)accU[ftl][ht][0]; h[1]=(_Float16)accU[ftl][ht][1];
            h[2]=(_Float16)accU[ftl][ht][2]; h[3]=(_Float16)accU[ftl][ht][3];
            uh[ftl][ht] = h;
        }

    float4_t sc[4][4];   // [ht][gt]
    #pragma unroll
    for (int i = 0; i < 4; ++i)
        #pragma unroll
        for (int j = 0; j < 4; ++j) sc[i][j] = (float4_t){0,0,0,0};

    #pragma unroll
    for (int ftl = 0; ftl < 4; ++ftl) {
        half4_t Bq[4];
        #pragma unroll
        for (int gt = 0; gt < 4; ++gt) {
            float4_t qv = *(const float4_t*)(qm + base + (long)(gt * 16 + r16) * 512
                                             + w * 64 + ftl * 16 + q4);
            half4_t h;
            h[0]=(_Float16)qv[0]; h[1]=(_Float16)qv[1]; h[2]=(_Float16)qv[2]; h[3]=(_Float16)qv[3];
            Bq[gt] = h;
        }
        #pragma unroll
        for (int ht = 0; ht < 4; ++ht)
            #pragma unroll
            for (int gt = 0; gt < 4; ++gt)
                sc[ht][gt] = MFMA16(uh[ftl][ht], Bq[gt], sc[ht][gt]);
    }

    // cross-wave reduction into sS
    #pragma unroll
    for (int ht = 0; ht < 4; ++ht)
        #pragma unroll
        for (int gt = 0; gt < 4; ++gt)
            #pragma unroll
            for (int j = 0; j < 4; ++j)
                atomicAdd(&sS[(ht * 16 + q4 + j) * SP + gt * 16 + r16], sc[ht][gt][j]);
    __syncthreads();

    // ---- softmax over g (waves 0-3: 16 rows each, 4 lanes/row) ----
    if (w < 4) {
        const int r  = w * 16 + r16;
        const int qd = lane >> 4;
        const float* srow = sS + r * SP + qd * 16;
        float v[16];
        float mx = -1e30f;
        #pragma unroll
        for (int i = 0; i < 16; ++i) { v[i] = srow[i]; mx = fmaxf(mx, v[i]); }
        mx = fmaxf(mx, __shfl_xor(mx, 16));
        mx = fmaxf(mx, __shfl_xor(mx, 32));
        float sum = 0.f;
        #pragma unroll
        for (int i = 0; i < 16; ++i) { v[i] = __expf(v[i] - mx); sum += v[i]; }
        sum += __shfl_xor(sum, 16);
        sum += __shfl_xor(sum, 32);
        const float inv = 1.0f / sum;
        float*    aout = out + CTX + ((long)b * 64 + r) * 64 + qd * 16;
        _Float16* prow = sP + r * PP + qd * 16;
        #pragma unroll
        for (int i = 0; i < 16; ++i) {
            float a = v[i] * inv;
            aout[i] = a;
            prow[i] = (_Float16)a;
        }
    }
    __syncthreads();

    // ---- phase 3: context = P @ Q, wave w owns e-slice [64w, 64w+64) ----
    float4_t acc[4][4];   // [ht][et]
    #pragma unroll
    for (int i = 0; i < 4; ++i)
        #pragma unroll
        for (int j = 0; j < 4; ++j) acc[i][j] = (float4_t){0,0,0,0};

    const int Eb = w * 64;
    #pragma unroll
    for (int kk = 0; kk < 4; ++kk) {
        half4_t aP[4], bQ[4];
        #pragma unroll
        for (int ht = 0; ht < 4; ++ht)
            aP[ht] = *(const half4_t*)(&sP[(ht * 16 + r16) * PP + kk * 16 + q4]);
        #pragma unroll
        for (int et = 0; et < 4; ++et) {
            half4_t h;
            #pragma unroll
            for (int j = 0; j < 4; ++j)
                h[j] = (_Float16)qm[base + (long)(kk * 16 + q4 + j) * 512 + Eb + et * 16 + r16];
            bQ[et] = h;
        }
        #pragma unroll
        for (int ht = 0; ht < 4; ++ht)
            #pragma unroll
            for (int et = 0; et < 4; ++et)
                acc[ht][et] = MFMA16(aP[ht], bQ[et], acc[ht][et]);
    }

    // ---- store context (f32) ----
    #pragma unroll
    for (int ht = 0; ht < 4; ++ht)
        #pragma unroll
        for (int j = 0; j < 4; ++j) {
            const long row = (long)b * 64 + ht * 16 + q4 + j;
            float* orow = out + row * 512 + Eb;
            #pragma unroll
            for (int et = 0; et < 4; ++et)
                orow[et * 16 + r16] = acc[ht][et][j];
        }
}

extern "C" void kernel_launch(void* const* d_in, const int* in_sizes, int n_in,
                              void* d_out, int out_size, void* d_ws, size_t ws_size,
                              hipStream_t stream) {
    const float* o1 = (const float*)d_in[0];
    const float* o2 = (const float*)d_in[1];
    const float* o3 = (const float*)d_in[2];
    const float* qm = (const float*)d_in[3];
    const float* W  = (const float*)d_in[4];
    float* out = (float*)d_out;
    _Float16* W2 = (_Float16*)d_ws;       // 512 KB fragment-layout fp16 W

    w_pack<<<dim3(256), dim3(256), 0, stream>>>(W, W2);
    ovo_main<<<dim3(Bb), dim3(512), 0, stream>>>(o1, o2, o3, qm, W2, out);
}